// Round 9
// baseline (92.331 us; speedup 1.0000x reference)
//
#include <hip/hip_runtime.h>

// QSP via Laurent polynomial, one kernel (R19).
// Math = R18 (validated): u00 = sum_k P_k cos((2k+1)th) + Q_k sin((2k+1)th),
// coupled 3-term recurrences, K = 2cos2th; gamma via designated-wave
// recurrence + LDS handoff.
// R19 delta: occupancy probe at constant work. 512-thread blocks, grid 1024,
// E=4 -> 32 waves/CU = 8 waves/SIMD (hw max), still exactly ONE gamma chain
// per SIMD (4 blocks/CU, gwv = blockIdx&3 -> distinct SIMDs). Per-SIMD issue
// work unchanged (~16us); busy% should rise ~50% -> ~80%, kernel ~35 -> ~20us.
// If dur stays ~90: the ~52us harness floor (268MB poison fill @ 81% HBM +
// launch overhead) dominates and kernel time is no longer the lever.

__device__ __forceinline__ float wave_shr1(float x) {
    // lane L <- lane L-1, lane 0 <- 0 (DPP wave_shr:1, bound_ctrl=1)
    return __builtin_bit_cast(float,
        __builtin_amdgcn_update_dpp(0, __builtin_bit_cast(int, x),
                                    0x138, 0xf, 0xf, true));
}

__device__ __forceinline__ float rlane(float x, int l) {
    // broadcast lane l's value to all lanes (l must be wave-uniform)
    return __builtin_bit_cast(float,
        __builtin_amdgcn_readlane(__builtin_bit_cast(int, x), l));
}

__global__ __launch_bounds__(512, 8) void qsp_fused(
    const float* __restrict__ th,
    const float* __restrict__ phis,
    float* __restrict__ out,    // [0,B): real, [B,2B): imag
    int Bq4)                     // B/4
{
    __shared__ float2 gsh2[128];   // gamma_t, t = 0..127

    const int tid  = threadIdx.x;
    const int lane = tid & 63;
    const int wv   = tid >> 6;          // 0..7
    const int gwv  = blockIdx.x & 3;    // designated gamma wave -> SIMD gwv
    const int idx  = blockIdx.x * blockDim.x + tid;
    const int lidx = (idx < Bq4) ? idx : 0;

    // issue theta load first; latency hides under gamma/prologue
    const float4 ta = ((const float4*)th)[lidx];

    if (wv == gwv) {
        // ---- gamma recurrence (validated R6-R18), this wave only -----------
        float sp, cp;
        __sincosf(phis[lane], &sp, &cp);
        const float hAx = 0.5f * cp, hAy = 0.5f * sp;        // k = lane
        __sincosf(phis[lane + 64], &sp, &cp);
        const float hBx = 0.5f * cp, hBy = 0.5f * sp;        // k = lane + 64

        float A0r = 0.f, A0i = 0.f, B0r = 0.f, B0i = 0.f;
        float A1r = 0.f, A1i = 0.f, B1r = 0.f, B1i = 0.f;
        const float h0x = rlane(hAx, 0), h0y = rlane(hAy, 0);
        if (lane == 0) { A0r = 2.f * h0x; A0i = 2.f * h0y; } // A[0] = e_0

        #define QSP_REC(hx_, hy_)                                             \
        {                                                                     \
            const float hx = (hx_), hy = (hy_);                               \
            const float pAr = wave_shr1(A1r), pAi = wave_shr1(A1i);           \
            const float pBr = wave_shr1(B1r), pBi = wave_shr1(B1i);           \
            const float u0r = pAr + pBr, u0i = pAi + pBi;                     \
            const float v0r = A0r - B0r, v0i = A0i - B0i;                     \
            const float sA0r = u0r + v0r, sA0i = u0i + v0i;                   \
            const float sB0r = u0r - v0r, sB0i = u0i - v0i;                   \
            const float u1r = A0r + B0r, u1i = A0i + B0i;                     \
            const float v1r = A1r - B1r, v1i = A1i - B1i;                     \
            const float sA1r = u1r + v1r, sA1i = u1i + v1i;                   \
            const float sB1r = u1r - v1r, sB1i = u1i - v1i;                   \
            A0r = fmaf(hx, sA0r, -hy * sA0i);                                 \
            A0i = fmaf(hx, sA0i,  hy * sA0r);                                 \
            B0r = fmaf(hx, sB0r,  hy * sB0i);                                 \
            B0i = fmaf(hx, sB0i, -hy * sB0r);                                 \
            A1r = fmaf(hx, sA1r, -hy * sA1i);                                 \
            A1i = fmaf(hx, sA1i,  hy * sA1r);                                 \
            B1r = fmaf(hx, sB1r,  hy * sB1i);                                 \
            B1i = fmaf(hx, sB1i, -hy * sB1r);                                 \
        }
        #pragma unroll 4
        for (int k = 1; k < 64; ++k)   QSP_REC(rlane(hAx, k), rlane(hAy, k))
        #pragma unroll 4
        for (int k = 0; k < 64; ++k)   QSP_REC(rlane(hBx, k), rlane(hBy, k))
        #undef QSP_REC

        // gamma_{2L}, gamma_{2L+1} -> one 16B store (16B-aligned: 2L even)
        *(float4*)&gsh2[2 * lane] = make_float4(A0r, A0i, A1r, A1i);
    }

    // ---- per-thread prologue (all waves; overlaps gamma wave's chain) ------
    // seeds: c1 = cos th, s1 = sin th; prev = cos(-th), sin(-th); K = 2cos2th
    const float th4[4] = {ta.x, ta.y, ta.z, ta.w};
    float c0v[4], c1v[4], s0v[4], s1v[4], Kv[4], accr[4], acci[4];
    #pragma unroll
    for (int e = 0; e < 4; ++e) {
        float s, c;
        __sincosf(th4[e], &s, &c);
        c1v[e] = c;  s1v[e] = s;
        c0v[e] = c;  s0v[e] = -s;                 // k = -1 terms
        Kv[e]  = fmaf(-4.f * s, s, 2.f);          // 2 cos 2th = 2 - 4 sin^2
        accr[e] = 0.f; acci[e] = 0.f;
    }

    __syncthreads();

    // lane k derives its own (P_k, Q_k) from gamma (one-time, 2x ds_read_b64)
    const float2 ga = gsh2[63 - lane];            // gamma_{63-k}
    const float2 gb = gsh2[64 + lane];            // gamma_{64+k}
    const float Pr = ga.x + gb.x, Pi = ga.y + gb.y;
    const float Qr = ga.y - gb.y, Qi = gb.x - ga.x;

    // ---- harmonic sum, k = 0..63 (m = 2k+1); coeffs via readlane -----------
    #pragma unroll 2
    for (int k = 0; k < 64; ++k) {
        const float pr = rlane(Pr, k), pi = rlane(Pi, k);
        const float qr = rlane(Qr, k), qi = rlane(Qi, k);
        #pragma unroll
        for (int e = 0; e < 4; ++e) {
            accr[e] = fmaf(pr, c1v[e], fmaf(qr, s1v[e], accr[e]));
            acci[e] = fmaf(pi, c1v[e], fmaf(qi, s1v[e], acci[e]));
            const float cn = fmaf(Kv[e], c1v[e], -c0v[e]);
            const float sn = fmaf(Kv[e], s1v[e], -s0v[e]);
            c0v[e] = c1v[e]; c1v[e] = cn;
            s0v[e] = s1v[e]; s1v[e] = sn;
        }
    }

    if (idx < Bq4) {
        float4* o4 = (float4*)out;
        o4[idx]       = make_float4(accr[0], accr[1], accr[2], accr[3]);
        o4[Bq4 + idx] = make_float4(acci[0], acci[1], acci[2], acci[3]);
    }
}

extern "C" void kernel_launch(void* const* d_in, const int* in_sizes, int n_in,
                              void* d_out, int out_size, void* d_ws, size_t ws_size,
                              hipStream_t stream)
{
    const float* th   = (const float*)d_in[0];
    const float* phis = (const float*)d_in[1];
    float* out = (float*)d_out;
    const int B = in_sizes[0];          // 2097152
    const int Bq4 = B >> 2;             // 524288 threads
    const int block = 512;              // 8 waves
    const int grid = (Bq4 + block - 1) / block;   // 1024 blocks = 4/CU, 32 waves/CU
    qsp_fused<<<grid, block, 0, stream>>>(th, phis, out, Bq4);
}